// Round 16
// baseline (269.054 us; speedup 1.0000x reference)
//
#include <hip/hip_runtime.h>
#include <hip/hip_bf16.h>
#include <cfloat>
#include <math.h>

// ---------------- types ----------------
typedef int   int32x4 __attribute__((ext_vector_type(4)));

#define AMSM_MARGIN 0.35f
#define AMSM_SCALE  30.0f
#define AMSM_EPS    1e-12f
#define L2E         1.4426950408889634f
#define BEXP        (-AMSM_SCALE * L2E)          // exp(logit-30) = exp2(f*acc + BEXP)
#define PADC        8.9833181e-12f               // 96 * exp(-30): pad-column constant

// ------------- kernel 1/2: row-normalize f32 -> per-row-scaled i8 ---------
__global__ __launch_bounds__(256) void rownorm_i8(
    const float* __restrict__ src, signed char* __restrict__ dst,
    float* __restrict__ scale, int nrows, int nrows_pad)
{
    int row  = blockIdx.x * 4 + (threadIdx.x >> 6);
    int lane = threadIdx.x & 63;
    if (row >= nrows_pad) return;

    signed char* drow = dst + (size_t)row * 512 + lane * 8;

    if (row >= nrows) {           // zero-fill pad rows
        *(int2*)drow = make_int2(0, 0);
        if (lane == 0) scale[row] = 0.f;
        return;
    }
    const float4* p = (const float4*)(src + (size_t)row * 512 + lane * 8);
    float4 a = p[0], b = p[1];
    float ss = a.x*a.x + a.y*a.y + a.z*a.z + a.w*a.w
             + b.x*b.x + b.y*b.y + b.z*b.z + b.w*b.w;
    #pragma unroll
    for (int m = 1; m < 64; m <<= 1) ss += __shfl_xor(ss, m, 64);
    float r = 1.0f / sqrtf(ss + AMSM_EPS);

    float v[8] = { a.x*r, a.y*r, a.z*r, a.w*r, b.x*r, b.y*r, b.z*r, b.w*r };
    float mx = 0.f;
    #pragma unroll
    for (int i = 0; i < 8; ++i) mx = fmaxf(mx, fabsf(v[i]));
    #pragma unroll
    for (int m = 1; m < 64; m <<= 1) mx = fmaxf(mx, __shfl_xor(mx, m, 64));
    float qs = 127.0f / mx;       // mx >= 1/sqrt(512) > 0 for a unit vector

    int q[8];
    #pragma unroll
    for (int i = 0; i < 8; ++i) {
        float t = rintf(v[i] * qs);
        t = fmaxf(-127.f, fminf(127.f, t));
        q[i] = (int)t;
    }
    unsigned int lo32 = (q[0]&255) | ((q[1]&255)<<8) | ((q[2]&255)<<16) | ((unsigned)(q[3]&255)<<24);
    unsigned int hi32 = (q[4]&255) | ((q[5]&255)<<8) | ((q[6]&255)<<16) | ((unsigned)(q[7]&255)<<24);
    *(int2*)drow = make_int2((int)lo32, (int)hi32);
    if (lane == 0) scale[row] = mx * (1.0f / 127.0f);
}

// ------------- kernel 2b: exact target logit (margined) per row -----------
__global__ __launch_bounds__(256) void target_logit(
    const signed char* __restrict__ xq, const signed char* __restrict__ Wq,
    const float* __restrict__ sa, const float* __restrict__ sb,
    const int* __restrict__ lb, float* __restrict__ tgt, int N)
{
    int n    = blockIdx.x * 4 + (threadIdx.x >> 6);
    int lane = threadIdx.x & 63;
    if (n >= N) return;
    const int c = lb[n];
    int2 a = *(const int2*)(xq + (size_t)n * 512 + lane * 8);
    int2 b = *(const int2*)(Wq + (size_t)c * 512 + lane * 8);
    int d = 0;
    #pragma unroll
    for (int i = 0; i < 4; ++i)
        d += ((a.x << (24 - 8*i)) >> 24) * ((b.x << (24 - 8*i)) >> 24);
    #pragma unroll
    for (int i = 0; i < 4; ++i)
        d += ((a.y << (24 - 8*i)) >> 24) * ((b.y << (24 - 8*i)) >> 24);
    #pragma unroll
    for (int m = 1; m < 64; m <<= 1) d += __shfl_xor(d, m, 64);
    if (lane == 0)
        tgt[n] = AMSM_SCALE * sa[n] * sb[c] * (float)d - AMSM_SCALE * AMSM_MARGIN;
}

// ---------------- kernel 3: 128x128 i8 GEMM, B streamed around LDS --------
// r15 change: LDS port was the dominant pipe (~60% busy, 1.5x MFMA demand).
// B-fragments are loaded DIRECTLY global->VGPR (canonical MFMA layout:
// lane(g,lo) holds B[col][kt*64+g*16..+15]; 4-lane clusters read 64B
// contiguous; L2-resident via T1 swizzle). A stays in LDS (double-buffered
// 16KB, T2-swizzled as verified 0-conflict). B double-buffered in NAMED reg
// sets (no runtime indexing). Counted waits per phase (issue order
// [A-stage2, SB, Bload4]): VMC(6) pre-MFMA drains B(t); VMC(4) pre-BAR
// drains A-stage(t+1), keeps B(t+1) in flight. sched_barrier(0) fences
// MFMA hoisting past the inline-asm waits.
#define CTILES 782    // 100096 / 128

__device__ __forceinline__ void load_lds16(const void* g, void* l) {
    __builtin_amdgcn_global_load_lds(
        (const __attribute__((address_space(1))) void*)g,
        (__attribute__((address_space(3))) void*)l, 16, 0, 0);
}

#define BAR() __builtin_amdgcn_s_barrier()
#define VMC(N) asm volatile("s_waitcnt vmcnt(" #N ")" ::: "memory")
#define SB0() __builtin_amdgcn_sched_barrier(0)

__global__ __launch_bounds__(256, 3) void amsm_gemm(
    const signed char* __restrict__ xq, const signed char* __restrict__ Wq,
    const float* __restrict__ sa, const float* __restrict__ sb,
    float* __restrict__ psum, int CHUNKS)
{
    __shared__ char lds[16384];   // A only: [2][8192], each [128 rows][64B]

    // T1: bijective XCD swizzle (12512 = 8 * 1564)
    const int bid = blockIdx.x;
    const int wid = (bid & 7) * 1564 + (bid >> 3);
    const int mt  = wid & 15;           // m fast -> same-XCD blocks share W band
    const int ct  = wid >> 4;
    const int m0  = mt * 128;
    const int c0  = ct * 128;

    const int tid  = threadIdx.x;
    const int lane = tid & 63;
    const int w    = tid >> 6;
    const int wr   = w >> 1;            // 0..1 (M)
    const int wc   = w & 1;             // 0..1 (N)
    const int g    = lane >> 4;
    const int lo   = lane & 15;

    const signed char* gA = xq + (size_t)m0 * 512;

    // stage tile kt's A (8KB = 2 instrs/thread of 16B), T2-swizzled source
    auto stageA = [&](int b, int kt) {
        #pragma unroll
        for (int iss = 0; iss < 2; ++iss) {
            const int q   = iss * 256 + tid;        // 512 x 16B = 128 rows x 64B
            const int row = q >> 2;
            const int kc  = (q & 3) ^ ((q >> 4) & 2);
            load_lds16(gA + (size_t)row * 512 + kt * 64 + kc * 16,
                       lds + b * 8192 + q * 16);
        }
    };

    const int kxb  = (g ^ ((lo >> 2) & 2)) * 16;    // T2 involution (read), bytes
    const int aoff = (wr * 64 + lo) * 64 + kxb;     // byte off within A region

    // B base pointers: frag ni, lane(g,lo) -> row c0+wc*64+ni*16+lo, col g*16
    const signed char* bp0 = Wq + (size_t)(c0 + wc * 64 + lo) * 512 + g * 16;
    const signed char* bp1 = bp0 + 16 * 512;
    const signed char* bp2 = bp0 + 32 * 512;
    const signed char* bp3 = bp0 + 48 * 512;

    int32x4 acc[4][4] = {};
    int32x4 af[4];
    int32x4 bX0, bX1, bX2, bX3, bY0, bY1, bY2, bY3;

#define LDA(B) { const char* rb_ = lds + (B)*8192 + aoff; \
    _Pragma("unroll") for (int mi_ = 0; mi_ < 4; ++mi_) \
        af[mi_] = *(const int32x4*)(rb_ + mi_*1024); }
#define BLOAD(DST, BP, KOFF) asm volatile( \
    "global_load_dwordx4 %0, %1, off offset:" KOFF \
    : "=&v"(DST) : "v"(BP) : "memory")
#define MM16(B0,B1,B2,B3) __builtin_amdgcn_s_setprio(1); \
    _Pragma("unroll") for (int mi_ = 0; mi_ < 4; ++mi_) { \
        acc[mi_][0] = __builtin_amdgcn_mfma_i32_16x16x64_i8(af[mi_], B0, acc[mi_][0],0,0,0); \
        acc[mi_][1] = __builtin_amdgcn_mfma_i32_16x16x64_i8(af[mi_], B1, acc[mi_][1],0,0,0); \
        acc[mi_][2] = __builtin_amdgcn_mfma_i32_16x16x64_i8(af[mi_], B2, acc[mi_][2],0,0,0); \
        acc[mi_][3] = __builtin_amdgcn_mfma_i32_16x16x64_i8(af[mi_], B3, acc[mi_][3],0,0,0); } \
    __builtin_amdgcn_s_setprio(0);
// phase t (t=0..6): cur buf CB holds A(t); stage A(t+1)->NB; load B(t+1)->N*;
// MFMA with U* = B(t). VMC(6): drain B(t) [A(t+1)2+B(t+1)4 stay]. VMC(4):
// drain A(t+1) [B(t+1) stays]. BAR publishes A(t+1).
#define PHASE(CB, NB, KT1, KOFF, U0,U1,U2,U3, N0,N1,N2,N3) \
    stageA(NB, KT1); \
    SB0(); \
    BLOAD(N0, bp0, KOFF); BLOAD(N1, bp1, KOFF); \
    BLOAD(N2, bp2, KOFF); BLOAD(N3, bp3, KOFF); \
    LDA(CB); \
    VMC(6); \
    SB0(); \
    MM16(U0,U1,U2,U3); \
    VMC(4); \
    BAR();

    // ---- prologue: A(0)->buf0, B(0)->bX ----
    stageA(0, 0);
    SB0();
    BLOAD(bX0, bp0, "0"); BLOAD(bX1, bp1, "0");
    BLOAD(bX2, bp2, "0"); BLOAD(bX3, bp3, "0");
    VMC(0); BAR();

    // ---- 8 K-steps (BK=64) ----
    PHASE(0, 1, 1, "64",  bX0,bX1,bX2,bX3, bY0,bY1,bY2,bY3);   // t=0
    PHASE(1, 0, 2, "128", bY0,bY1,bY2,bY3, bX0,bX1,bX2,bX3);   // t=1
    PHASE(0, 1, 3, "192", bX0,bX1,bX2,bX3, bY0,bY1,bY2,bY3);   // t=2
    PHASE(1, 0, 4, "256", bY0,bY1,bY2,bY3, bX0,bX1,bX2,bX3);   // t=3
    PHASE(0, 1, 5, "320", bX0,bX1,bX2,bX3, bY0,bY1,bY2,bY3);   // t=4
    PHASE(1, 0, 6, "384", bY0,bY1,bY2,bY3, bX0,bX1,bX2,bX3);   // t=5
    PHASE(0, 1, 7, "448", bX0,bX1,bX2,bX3, bY0,bY1,bY2,bY3);   // t=6
    // t=7: last tile (buf1, bY); drain B(7), no staging
    LDA(1);
    VMC(0);
    SB0();
    MM16(bY0,bY1,bY2,bY3);

    // ---- epilogue ----
    const int n_base = m0 + wr * 64;
    const int c_base = c0 + wc * 64;
    const int chunk  = ct * 2 + wc;

    float sbv[4];
    #pragma unroll
    for (int ni = 0; ni < 4; ++ni) sbv[ni] = sb[c_base + ni * 16 + lo];

    // v16[r], r = mi*4+j  <->  row n = n_base + (r>>2)*16 + g*4 + (r&3)
    float v16[16];
    #pragma unroll
    for (int mi = 0; mi < 4; ++mi) {
        float4 sa4 = *(const float4*)(sa + n_base + mi * 16 + g * 4);
        const float* sap = (const float*)&sa4;
        #pragma unroll
        for (int j = 0; j < 4; ++j) {
            const float stf = (AMSM_SCALE * L2E) * sap[j];
            float s = 0.f;
            #pragma unroll
            for (int ni = 0; ni < 4; ++ni)
                s += __builtin_amdgcn_exp2f(
                        fmaf((float)acc[mi][ni][j], stf * sbv[ni], BEXP));
            v16[mi * 4 + j] = s;
        }
    }

    // value-halving butterfly over the 16 lo-lanes: lane lo ends with row lo
    const int b0 = lo & 1, b1 = (lo >> 1) & 1, b2 = (lo >> 2) & 1, b3 = (lo >> 3) & 1;
    float v8[8];
    #pragma unroll
    for (int k = 0; k < 8; ++k) {
        float keep = b0 ? v16[2*k+1] : v16[2*k];
        float send = b0 ? v16[2*k]   : v16[2*k+1];
        v8[k] = keep + __shfl_xor(send, 1, 64);
    }
    float v4[4];
    #pragma unroll
    for (int k = 0; k < 4; ++k) {
        float keep = b1 ? v8[2*k+1] : v8[2*k];
        float send = b1 ? v8[2*k]   : v8[2*k+1];
        v4[k] = keep + __shfl_xor(send, 2, 64);
    }
    float v2[2];
    #pragma unroll
    for (int k = 0; k < 2; ++k) {
        float keep = b2 ? v4[2*k+1] : v4[2*k];
        float send = b2 ? v4[2*k]   : v4[2*k+1];
        v2[k] = keep + __shfl_xor(send, 4, 64);
    }
    {
        float keep = b3 ? v2[1] : v2[0];
        float send = b3 ? v2[0] : v2[1];
        float vt = keep + __shfl_xor(send, 8, 64);
        const int n_out = n_base + (lo >> 2) * 16 + g * 4 + (lo & 3);
        psum[(size_t)n_out * CHUNKS + chunk] = vt;
    }
#undef LDA
#undef BLOAD
#undef MM16
#undef PHASE
}

// ---------------- kernel 4: per-row combine + margin fix-up ----------------
__global__ __launch_bounds__(256) void row_reduce(
    const float* __restrict__ psum, const float* __restrict__ tgt,
    float* __restrict__ row_loss, int CHUNKS)
{
    const int n = blockIdx.x;
    const int tid = threadIdx.x;
    __shared__ float sm[256];

    float s = 0.f;
    for (int j = tid; j < CHUNKS; j += 256) s += psum[(size_t)n * CHUNKS + j];
    sm[tid] = s; __syncthreads();
    for (int st = 128; st > 0; st >>= 1) {
        if (tid < st) sm[tid] += sm[tid + st];
        __syncthreads();
    }
    if (tid == 0) {
        const float tl = tgt[n];                       // margined target logit
        float S = sm[0] - PADC - expf(tl - (AMSM_SCALE - AMSM_SCALE*AMSM_MARGIN))
                + expf(tl - AMSM_SCALE);
        row_loss[n] = (logf(S) + AMSM_SCALE) - tl;
    }
}

// ---------------- kernel 5: mean over rows -> scalar ----------------
__global__ __launch_bounds__(256) void final_reduce(
    const float* __restrict__ row_loss, float* __restrict__ out, int N)
{
    const int tid = threadIdx.x;
    __shared__ float sm[256];
    float s = 0.f;
    for (int i = tid; i < N; i += 256) s += row_loss[i];
    sm[tid] = s; __syncthreads();
    for (int st = 128; st > 0; st >>= 1) {
        if (tid < st) sm[tid] += sm[tid + st];
        __syncthreads();
    }
    if (tid == 0) out[0] = sm[0] / (float)N;
}

// ---------------- launch ----------------
extern "C" void kernel_launch(void* const* d_in, const int* in_sizes, int n_in,
                              void* d_out, int out_size, void* d_ws, size_t ws_size,
                              hipStream_t stream) {
    const float* x  = (const float*)d_in[0];
    const float* W  = (const float*)d_in[1];
    const int*   lb = (const int*)d_in[2];
    float* out = (float*)d_out;

    constexpr int N  = 2048, D = 512, C = 100000;
    constexpr int C_PAD  = CTILES * 128;     // 100096
    constexpr int CHUNKS = CTILES * 2;       // 1564 (one per 64-col wave stripe)

    char* ws = (char*)d_ws;
    auto alloc = [&](size_t bytes) {
        char* p = ws; ws += (bytes + 255) & ~(size_t)255; return p;
    };
    signed char* Wq  = (signed char*)alloc((size_t)C_PAD * D);          // 51.2 MB
    signed char* xqv = (signed char*)alloc((size_t)N * D);              // 1 MB
    float*  sw   = (float*)alloc((size_t)C_PAD * sizeof(float));        // 400 KB
    float*  sx   = (float*)alloc((size_t)N * sizeof(float));
    float*  psum = (float*)alloc((size_t)N * CHUNKS * sizeof(float));   // 12.8 MB
    float*  tgtv = (float*)alloc((size_t)N * sizeof(float));
    float*  rl   = (float*)alloc((size_t)N * sizeof(float));

    rownorm_i8<<<N / 4, 256, 0, stream>>>(x, xqv, sx, N, N);
    rownorm_i8<<<C_PAD / 4, 256, 0, stream>>>(W, Wq, sw, C, C_PAD);
    target_logit<<<N / 4, 256, 0, stream>>>(xqv, Wq, sx, sw, lb, tgtv, N);

    amsm_gemm<<<16 * CTILES, 256, 0, stream>>>(xqv, Wq, sx, sw, psum, CHUNKS);

    row_reduce<<<N, 256, 0, stream>>>(psum, tgtv, rl, CHUNKS);
    final_reduce<<<1, 256, 0, stream>>>(rl, out, N);
}

// Round 17
// 179.768 us; speedup vs baseline: 1.4967x; 1.4967x over previous
//
#include <hip/hip_runtime.h>
#include <hip/hip_bf16.h>
#include <cfloat>
#include <math.h>

// ---------------- types ----------------
typedef int   int32x4 __attribute__((ext_vector_type(4)));

#define AMSM_MARGIN 0.35f
#define AMSM_SCALE  30.0f
#define AMSM_EPS    1e-12f
#define L2E         1.4426950408889634f
#define BEXP        (-AMSM_SCALE * L2E)          // exp(logit-30) = exp2(f*acc + BEXP)
#define PADC        8.9833181e-12f               // 96 * exp(-30): pad-column constant

// ------------- kernel 1/2: row-normalize f32 -> per-row-scaled i8 ---------
__global__ __launch_bounds__(256) void rownorm_i8(
    const float* __restrict__ src, signed char* __restrict__ dst,
    float* __restrict__ scale, int nrows, int nrows_pad)
{
    int row  = blockIdx.x * 4 + (threadIdx.x >> 6);
    int lane = threadIdx.x & 63;
    if (row >= nrows_pad) return;

    signed char* drow = dst + (size_t)row * 512 + lane * 8;

    if (row >= nrows) {           // zero-fill pad rows
        *(int2*)drow = make_int2(0, 0);
        if (lane == 0) scale[row] = 0.f;
        return;
    }
    const float4* p = (const float4*)(src + (size_t)row * 512 + lane * 8);
    float4 a = p[0], b = p[1];
    float ss = a.x*a.x + a.y*a.y + a.z*a.z + a.w*a.w
             + b.x*b.x + b.y*b.y + b.z*b.z + b.w*b.w;
    #pragma unroll
    for (int m = 1; m < 64; m <<= 1) ss += __shfl_xor(ss, m, 64);
    float r = 1.0f / sqrtf(ss + AMSM_EPS);

    float v[8] = { a.x*r, a.y*r, a.z*r, a.w*r, b.x*r, b.y*r, b.z*r, b.w*r };
    float mx = 0.f;
    #pragma unroll
    for (int i = 0; i < 8; ++i) mx = fmaxf(mx, fabsf(v[i]));
    #pragma unroll
    for (int m = 1; m < 64; m <<= 1) mx = fmaxf(mx, __shfl_xor(mx, m, 64));
    float qs = 127.0f / mx;       // mx >= 1/sqrt(512) > 0 for a unit vector

    int q[8];
    #pragma unroll
    for (int i = 0; i < 8; ++i) {
        float t = rintf(v[i] * qs);
        t = fmaxf(-127.f, fminf(127.f, t));
        q[i] = (int)t;
    }
    unsigned int lo32 = (q[0]&255) | ((q[1]&255)<<8) | ((q[2]&255)<<16) | ((unsigned)(q[3]&255)<<24);
    unsigned int hi32 = (q[4]&255) | ((q[5]&255)<<8) | ((q[6]&255)<<16) | ((unsigned)(q[7]&255)<<24);
    *(int2*)drow = make_int2((int)lo32, (int)hi32);
    if (lane == 0) scale[row] = mx * (1.0f / 127.0f);
}

// ------------- kernel 2b: exact target logit (margined) per row -----------
__global__ __launch_bounds__(256) void target_logit(
    const signed char* __restrict__ xq, const signed char* __restrict__ Wq,
    const float* __restrict__ sa, const float* __restrict__ sb,
    const int* __restrict__ lb, float* __restrict__ tgt, int N)
{
    int n    = blockIdx.x * 4 + (threadIdx.x >> 6);
    int lane = threadIdx.x & 63;
    if (n >= N) return;
    const int c = lb[n];
    int2 a = *(const int2*)(xq + (size_t)n * 512 + lane * 8);
    int2 b = *(const int2*)(Wq + (size_t)c * 512 + lane * 8);
    int d = 0;
    #pragma unroll
    for (int i = 0; i < 4; ++i)
        d += ((a.x << (24 - 8*i)) >> 24) * ((b.x << (24 - 8*i)) >> 24);
    #pragma unroll
    for (int i = 0; i < 4; ++i)
        d += ((a.y << (24 - 8*i)) >> 24) * ((b.y << (24 - 8*i)) >> 24);
    #pragma unroll
    for (int m = 1; m < 64; m <<= 1) d += __shfl_xor(d, m, 64);
    if (lane == 0)
        tgt[n] = AMSM_SCALE * sa[n] * sb[c] * (float)d - AMSM_SCALE * AMSM_MARGIN;
}

// -------- kernel 3: 128x256 i8 triple-buffered GEMM, fat register tile ----
// r17: back to the r12 LDS-staged triple-buffer structure (r15/16 B-direct
// refuted), ONE change vs r12: register blocking 4x4 -> 4x8 per wave with
// 4 waves/block (2Mx2N of 64x128). LDS-read : MFMA ratio drops 0.5 -> 0.375
// (12 ds_read_b128 per 32 MFMA) = 25% less traffic on the dominant pipe
// (LDS read port, ~60% busy in r12). Same 2 blocks/CU (72KB LDS, ~200 regs
// -> 2 waves/SIMD). Counted waits: 6 load-instrs/phase; VMC(6) drains the
// next-needed tile, keeps depth-2 prefetch in flight. T1/T2 unchanged.
#define CTILES 391    // 100096 / 256

__device__ __forceinline__ void load_lds16(const void* g, void* l) {
    __builtin_amdgcn_global_load_lds(
        (const __attribute__((address_space(1))) void*)g,
        (__attribute__((address_space(3))) void*)l, 16, 0, 0);
}

#define BAR() __builtin_amdgcn_s_barrier()
#define VMC(N) asm volatile("s_waitcnt vmcnt(" #N ")" ::: "memory")

__global__ __launch_bounds__(256, 2) void amsm_gemm(
    const signed char* __restrict__ xq, const signed char* __restrict__ Wq,
    const float* __restrict__ sa, const float* __restrict__ sb,
    float* __restrict__ psum, int CHUNKS)
{
    __shared__ char lds[73728];   // A: [3][8192] at 0; B: [3][16384] at 24576

    // T1: bijective XCD swizzle (6256 = 8 * 782)
    const int bid = blockIdx.x;
    const int wid = (bid & 7) * 782 + (bid >> 3);
    const int mt  = wid & 15;           // m fast -> same-XCD blocks share W band
    const int ct  = wid >> 4;
    const int m0  = mt * 128;
    const int c0  = ct * 256;

    const int tid  = threadIdx.x;
    const int lane = tid & 63;
    const int w    = tid >> 6;
    const int wr   = w >> 1;            // 0..1 (M, 64-row stripes)
    const int wc   = w & 1;             // 0..1 (N, 128-col stripes)
    const int g    = lane >> 4;
    const int lo   = lane & 15;

    const signed char* gA = xq + (size_t)m0 * 512;
    const signed char* gB = Wq + (size_t)c0 * 512;

    // stage tile kt: A 8KB (2 instrs/thread), B 16KB (4 instrs/thread)
    auto stageA = [&](int b, int kt) {
        #pragma unroll
        for (int iss = 0; iss < 2; ++iss) {
            const int q   = iss * 256 + tid;        // 512 x 16B = 128 rows x 64B
            const int row = q >> 2;
            const int kc  = (q & 3) ^ ((q >> 4) & 2);   // T2 involution (source)
            load_lds16(gA + (size_t)row * 512 + kt * 64 + kc * 16,
                       lds + b * 8192 + q * 16);
        }
    };
    auto stageB = [&](int b, int kt) {
        #pragma unroll
        for (int iss = 0; iss < 4; ++iss) {
            const int q   = iss * 256 + tid;        // 1024 x 16B = 256 rows x 64B
            const int row = q >> 2;
            const int kc  = (q & 3) ^ ((q >> 4) & 2);
            load_lds16(gB + (size_t)row * 512 + kt * 64 + kc * 16,
                       lds + 24576 + b * 16384 + q * 16);
        }
    };

    const int kxb  = (g ^ ((lo >> 2) & 2)) * 16;    // T2 involution (read), bytes
    const int aoff = (wr * 64  + lo) * 64 + kxb;    // byte off within A region
    const int boff = (wc * 128 + lo) * 64 + kxb;    // within B region (256 rows)

    int32x4 acc[4][8] = {};
    int32x4 af[4], bfr[8];

#define LDA(B) { const char* rb_ = lds + (B)*8192 + aoff; \
    _Pragma("unroll") for (int mi_ = 0; mi_ < 4; ++mi_) \
        af[mi_] = *(const int32x4*)(rb_ + mi_*1024); }
#define LDB(B) { const char* rb_ = lds + 24576 + (B)*16384 + boff; \
    _Pragma("unroll") for (int ni_ = 0; ni_ < 8; ++ni_) \
        bfr[ni_] = *(const int32x4*)(rb_ + ni_*1024); }
#define MM32() __builtin_amdgcn_s_setprio(1); \
    _Pragma("unroll") for (int mi_ = 0; mi_ < 4; ++mi_) \
      _Pragma("unroll") for (int ni_ = 0; ni_ < 8; ++ni_) \
        acc[mi_][ni_] = __builtin_amdgcn_mfma_i32_16x16x64_i8(af[mi_], bfr[ni_], acc[mi_][ni_], 0,0,0); \
    __builtin_amdgcn_s_setprio(0);
// phase t: read buf t%3 (12 ds_read), stage tile t+2 -> (t+2)%3 (6 loads),
// 32 MFMA, VMC(6) [drains stage(t+1)'s 6, keeps stage(t+2)'s 6], barrier.
#define PH3(BUF, SBUF, T2)  { LDA(BUF); LDB(BUF); stageA(SBUF, T2); stageB(SBUF, T2); \
    MM32(); VMC(6); BAR(); }

    // ---- prologue: tiles 0,1 -> bufs 0,1 (12 loads; drain tile0's 6) ----
    stageA(0, 0); stageB(0, 0);
    stageA(1, 1); stageB(1, 1);
    VMC(6); BAR();

    // ---- 8 K-steps (BK=64); phase t reads buf t%3, stages t+2 -> (t+2)%3 --
    PH3(0, 2, 2);   // t=0
    PH3(1, 0, 3);   // t=1
    PH3(2, 1, 4);   // t=2
    PH3(0, 2, 5);   // t=3
    PH3(1, 0, 6);   // t=4
    PH3(2, 1, 7);   // t=5
    LDA(0); LDB(0); MM32(); VMC(0); BAR();   // t=6 (drain tile7's stages)
    LDA(1); LDB(1); MM32();                  // t=7

    // ---- epilogue ----
    const int n_base = m0 + wr * 64;
    const int c_base = c0 + wc * 128;

    float sbv[8];
    #pragma unroll
    for (int ni = 0; ni < 8; ++ni) sbv[ni] = sb[c_base + ni * 16 + lo];

    #pragma unroll
    for (int h = 0; h < 2; ++h) {           // two 64-col chunks per wave
        const int chunk = ct * 4 + wc * 2 + h;
        // v16[r], r = mi*4+j  <->  row n = n_base + (r>>2)*16 + g*4 + (r&3)
        float v16[16];
        #pragma unroll
        for (int mi = 0; mi < 4; ++mi) {
            float4 sa4 = *(const float4*)(sa + n_base + mi * 16 + g * 4);
            const float* sap = (const float*)&sa4;
            #pragma unroll
            for (int j = 0; j < 4; ++j) {
                const float stf = (AMSM_SCALE * L2E) * sap[j];
                float s = 0.f;
                #pragma unroll
                for (int ni = 0; ni < 4; ++ni)
                    s += __builtin_amdgcn_exp2f(
                            fmaf((float)acc[mi][h * 4 + ni][j],
                                 stf * sbv[h * 4 + ni], BEXP));
                v16[mi * 4 + j] = s;
            }
        }
        // value-halving butterfly over 16 lo-lanes: lane lo ends with row lo
        const int b0 = lo & 1, b1 = (lo >> 1) & 1, b2 = (lo >> 2) & 1, b3 = (lo >> 3) & 1;
        float v8[8];
        #pragma unroll
        for (int k = 0; k < 8; ++k) {
            float keep = b0 ? v16[2*k+1] : v16[2*k];
            float send = b0 ? v16[2*k]   : v16[2*k+1];
            v8[k] = keep + __shfl_xor(send, 1, 64);
        }
        float v4[4];
        #pragma unroll
        for (int k = 0; k < 4; ++k) {
            float keep = b1 ? v8[2*k+1] : v8[2*k];
            float send = b1 ? v8[2*k]   : v8[2*k+1];
            v4[k] = keep + __shfl_xor(send, 2, 64);
        }
        float v2[2];
        #pragma unroll
        for (int k = 0; k < 2; ++k) {
            float keep = b2 ? v4[2*k+1] : v4[2*k];
            float send = b2 ? v4[2*k]   : v4[2*k+1];
            v2[k] = keep + __shfl_xor(send, 4, 64);
        }
        float keep = b3 ? v2[1] : v2[0];
        float send = b3 ? v2[0] : v2[1];
        float vt = keep + __shfl_xor(send, 8, 64);
        const int n_out = n_base + (lo >> 2) * 16 + g * 4 + (lo & 3);
        psum[(size_t)n_out * CHUNKS + chunk] = vt;
    }
#undef LDA
#undef LDB
#undef MM32
#undef PH3
}

// ---------------- kernel 4: per-row combine + margin fix-up ----------------
__global__ __launch_bounds__(256) void row_reduce(
    const float* __restrict__ psum, const float* __restrict__ tgt,
    float* __restrict__ row_loss, int CHUNKS)
{
    const int n = blockIdx.x;
    const int tid = threadIdx.x;
    __shared__ float sm[256];

    float s = 0.f;
    for (int j = tid; j < CHUNKS; j += 256) s += psum[(size_t)n * CHUNKS + j];
    sm[tid] = s; __syncthreads();
    for (int st = 128; st > 0; st >>= 1) {
        if (tid < st) sm[tid] += sm[tid + st];
        __syncthreads();
    }
    if (tid == 0) {
        const float tl = tgt[n];                       // margined target logit
        float S = sm[0] - PADC - expf(tl - (AMSM_SCALE - AMSM_SCALE*AMSM_MARGIN))
                + expf(tl - AMSM_SCALE);
        row_loss[n] = (logf(S) + AMSM_SCALE) - tl;
    }
}

// ---------------- kernel 5: mean over rows -> scalar ----------------
__global__ __launch_bounds__(256) void final_reduce(
    const float* __restrict__ row_loss, float* __restrict__ out, int N)
{
    const int tid = threadIdx.x;
    __shared__ float sm[256];
    float s = 0.f;
    for (int i = tid; i < N; i += 256) s += row_loss[i];
    sm[tid] = s; __syncthreads();
    for (int st = 128; st > 0; st >>= 1) {
        if (tid < st) sm[tid] += sm[tid + st];
        __syncthreads();
    }
    if (tid == 0) out[0] = sm[0] / (float)N;
}

// ---------------- launch ----------------
extern "C" void kernel_launch(void* const* d_in, const int* in_sizes, int n_in,
                              void* d_out, int out_size, void* d_ws, size_t ws_size,
                              hipStream_t stream) {
    const float* x  = (const float*)d_in[0];
    const float* W  = (const float*)d_in[1];
    const int*   lb = (const int*)d_in[2];
    float* out = (float*)d_out;

    constexpr int N  = 2048, D = 512, C = 100000;
    constexpr int C_PAD  = CTILES * 256;     // 100096
    constexpr int CHUNKS = CTILES * 4;       // 1564 (one per 64-col chunk)

    char* ws = (char*)d_ws;
    auto alloc = [&](size_t bytes) {
        char* p = ws; ws += (bytes + 255) & ~(size_t)255; return p;
    };
    signed char* Wq  = (signed char*)alloc((size_t)C_PAD * D);          // 51.2 MB
    signed char* xqv = (signed char*)alloc((size_t)N * D);              // 1 MB
    float*  sw   = (float*)alloc((size_t)C_PAD * sizeof(float));        // 400 KB
    float*  sx   = (float*)alloc((size_t)N * sizeof(float));
    float*  psum = (float*)alloc((size_t)N * CHUNKS * sizeof(float));   // 12.8 MB
    float*  tgtv = (float*)alloc((size_t)N * sizeof(float));
    float*  rl   = (float*)alloc((size_t)N * sizeof(float));

    rownorm_i8<<<N / 4, 256, 0, stream>>>(x, xqv, sx, N, N);
    rownorm_i8<<<C_PAD / 4, 256, 0, stream>>>(W, Wq, sw, C, C_PAD);
    target_logit<<<N / 4, 256, 0, stream>>>(xqv, Wq, sx, sw, lb, tgtv, N);

    amsm_gemm<<<16 * CTILES, 256, 0, stream>>>(xqv, Wq, sx, sw, psum, CHUNKS);

    row_reduce<<<N, 256, 0, stream>>>(psum, tgtv, rl, CHUNKS);
    final_reduce<<<1, 256, 0, stream>>>(rl, out, N);
}

// Round 18
// 178.035 us; speedup vs baseline: 1.5112x; 1.0097x over previous
//
#include <hip/hip_runtime.h>
#include <hip/hip_bf16.h>
#include <cfloat>
#include <math.h>

// ---------------- types ----------------
typedef int   int32x4 __attribute__((ext_vector_type(4)));

#define AMSM_MARGIN 0.35f
#define AMSM_SCALE  30.0f
#define AMSM_EPS    1e-12f
#define L2E         1.4426950408889634f
#define BEXP        (-AMSM_SCALE * L2E)          // exp(logit-30) = exp2(f*acc + BEXP)
#define PADC        8.9833181e-12f               // 96 * exp(-30): pad-column constant

// ------------- kernel 1/2: row-normalize f32 -> per-row-scaled i8 ---------
__global__ __launch_bounds__(256) void rownorm_i8(
    const float* __restrict__ src, signed char* __restrict__ dst,
    float* __restrict__ scale, int nrows, int nrows_pad)
{
    int row  = blockIdx.x * 4 + (threadIdx.x >> 6);
    int lane = threadIdx.x & 63;
    if (row >= nrows_pad) return;

    signed char* drow = dst + (size_t)row * 512 + lane * 8;

    if (row >= nrows) {           // zero-fill pad rows
        *(int2*)drow = make_int2(0, 0);
        if (lane == 0) scale[row] = 0.f;
        return;
    }
    const float4* p = (const float4*)(src + (size_t)row * 512 + lane * 8);
    float4 a = p[0], b = p[1];
    float ss = a.x*a.x + a.y*a.y + a.z*a.z + a.w*a.w
             + b.x*b.x + b.y*b.y + b.z*b.z + b.w*b.w;
    #pragma unroll
    for (int m = 1; m < 64; m <<= 1) ss += __shfl_xor(ss, m, 64);
    float r = 1.0f / sqrtf(ss + AMSM_EPS);

    float v[8] = { a.x*r, a.y*r, a.z*r, a.w*r, b.x*r, b.y*r, b.z*r, b.w*r };
    float mx = 0.f;
    #pragma unroll
    for (int i = 0; i < 8; ++i) mx = fmaxf(mx, fabsf(v[i]));
    #pragma unroll
    for (int m = 1; m < 64; m <<= 1) mx = fmaxf(mx, __shfl_xor(mx, m, 64));
    float qs = 127.0f / mx;       // mx >= 1/sqrt(512) > 0 for a unit vector

    int q[8];
    #pragma unroll
    for (int i = 0; i < 8; ++i) {
        float t = rintf(v[i] * qs);
        t = fmaxf(-127.f, fminf(127.f, t));
        q[i] = (int)t;
    }
    unsigned int lo32 = (q[0]&255) | ((q[1]&255)<<8) | ((q[2]&255)<<16) | ((unsigned)(q[3]&255)<<24);
    unsigned int hi32 = (q[4]&255) | ((q[5]&255)<<8) | ((q[6]&255)<<16) | ((unsigned)(q[7]&255)<<24);
    *(int2*)drow = make_int2((int)lo32, (int)hi32);
    if (lane == 0) scale[row] = mx * (1.0f / 127.0f);
}

// ------------- kernel 2b: exact target logit (margined) per row -----------
__global__ __launch_bounds__(256) void target_logit(
    const signed char* __restrict__ xq, const signed char* __restrict__ Wq,
    const float* __restrict__ sa, const float* __restrict__ sb,
    const int* __restrict__ lb, float* __restrict__ tgt, int N)
{
    int n    = blockIdx.x * 4 + (threadIdx.x >> 6);
    int lane = threadIdx.x & 63;
    if (n >= N) return;
    const int c = lb[n];
    int2 a = *(const int2*)(xq + (size_t)n * 512 + lane * 8);
    int2 b = *(const int2*)(Wq + (size_t)c * 512 + lane * 8);
    int d = 0;
    #pragma unroll
    for (int i = 0; i < 4; ++i)
        d += ((a.x << (24 - 8*i)) >> 24) * ((b.x << (24 - 8*i)) >> 24);
    #pragma unroll
    for (int i = 0; i < 4; ++i)
        d += ((a.y << (24 - 8*i)) >> 24) * ((b.y << (24 - 8*i)) >> 24);
    #pragma unroll
    for (int m = 1; m < 64; m <<= 1) d += __shfl_xor(d, m, 64);
    if (lane == 0)
        tgt[n] = AMSM_SCALE * sa[n] * sb[c] * (float)d - AMSM_SCALE * AMSM_MARGIN;
}

// ---------------- kernel 3: 128x256 i8 triple-buffered GEMM + sum-exp -----
// TERMINAL CONFIG (= r12, session best: 177.7 us total, GEMM ~130 us).
// 8 waves (2Mx4N of 64x64), BK=64, LDS 72KB triple-buffered (A 3x8KB,
// B 3x16KB), 2 blocks/CU, depth-2 prefetch w/ counted VMC(3), T1 XCD
// swizzle, T2 LDS swizzle (0 conflicts), native v_exp_f32 epilogue,
// value-halving butterfly reduce. Structural note: LDS-read(62us) + MFMA
// (53us) + writes/VALU sum ~= measured; 6 overlap attempts (r5/6/8/14/16/17)
// all null or negative -- pipes do not overlap at HIP source level for this
// short-K (8-tile) shape. r7 (2 blocks/CU) and r9 (i8) were the wins.
#define CTILES 391    // 100096 / 256

__device__ __forceinline__ void load_lds16(const void* g, void* l) {
    __builtin_amdgcn_global_load_lds(
        (const __attribute__((address_space(1))) void*)g,
        (__attribute__((address_space(3))) void*)l, 16, 0, 0);
}

#define BAR() __builtin_amdgcn_s_barrier()
#define VMC(N) asm volatile("s_waitcnt vmcnt(" #N ")" ::: "memory")

__global__ __launch_bounds__(512, 4) void amsm_gemm(
    const signed char* __restrict__ xq, const signed char* __restrict__ Wq,
    const float* __restrict__ sa, const float* __restrict__ sb,
    float* __restrict__ psum, int CHUNKS)
{
    __shared__ char lds[73728];   // A: [3][8192] at 0; B: [3][16384] at 24576

    // T1: bijective XCD swizzle (6256 = 8 * 782)
    const int bid = blockIdx.x;
    const int wid = (bid & 7) * 782 + (bid >> 3);
    const int mt  = wid & 15;           // m fast -> same-XCD blocks share W band
    const int ct  = wid >> 4;
    const int m0  = mt * 128;
    const int c0  = ct * 256;

    const int tid  = threadIdx.x;
    const int lane = tid & 63;
    const int w    = tid >> 6;
    const int wr   = w >> 2;            // 0..1 (M)
    const int wc   = w & 3;             // 0..3 (N)
    const int g    = lane >> 4;
    const int lo   = lane & 15;

    const signed char* gA = xq + (size_t)m0 * 512;
    const signed char* gB = Wq + (size_t)c0 * 512;

    auto stageA = [&](int b, int kt) {
        const int q   = tid;                        // 512 x 16B = 128 rows x 64B
        const int row = q >> 2;
        const int kc  = (q & 3) ^ ((q >> 4) & 2);   // T2 involution (source)
        load_lds16(gA + (size_t)row * 512 + kt * 64 + kc * 16,
                   lds + b * 8192 + q * 16);
    };
    auto stageB = [&](int b, int kt) {
        #pragma unroll
        for (int iss = 0; iss < 2; ++iss) {
            const int q   = iss * 512 + tid;        // 1024 x 16B = 256 rows x 64B
            const int row = q >> 2;
            const int kc  = (q & 3) ^ ((q >> 4) & 2);
            load_lds16(gB + (size_t)row * 512 + kt * 64 + kc * 16,
                       lds + 24576 + b * 16384 + q * 16);
        }
    };

    const int kxb  = (g ^ ((lo >> 2) & 2)) * 16;    // T2 involution (read), bytes
    const int aoff = (wr * 64 + lo) * 64 + kxb;     // byte off within A region
    const int boff = (wc * 64 + lo) * 64 + kxb;     // within B region

    int32x4 acc[4][4] = {};
    int32x4 af[4], bfr[4];

#define LDA(B) { const char* rb_ = lds + (B)*8192 + aoff; \
    _Pragma("unroll") for (int mi_ = 0; mi_ < 4; ++mi_) \
        af[mi_] = *(const int32x4*)(rb_ + mi_*1024); }
#define LDB(B) { const char* rb_ = lds + 24576 + (B)*16384 + boff; \
    _Pragma("unroll") for (int ni_ = 0; ni_ < 4; ++ni_) \
        bfr[ni_] = *(const int32x4*)(rb_ + ni_*1024); }
#define MM16() __builtin_amdgcn_s_setprio(1); \
    _Pragma("unroll") for (int mi_ = 0; mi_ < 4; ++mi_) \
      _Pragma("unroll") for (int ni_ = 0; ni_ < 4; ++ni_) \
        acc[mi_][ni_] = __builtin_amdgcn_mfma_i32_16x16x64_i8(af[mi_], bfr[ni_], acc[mi_][ni_], 0,0,0); \
    __builtin_amdgcn_s_setprio(0);
#define PH3(BUF, SBUF, T2)  { LDA(BUF); LDB(BUF); stageA(SBUF, T2); stageB(SBUF, T2); \
    MM16(); VMC(3); BAR(); }

    // ---- prologue: tiles 0,1 -> bufs 0,1 (6 loads; drain tile0's 3) ----
    stageA(0, 0); stageB(0, 0);
    stageA(1, 1); stageB(1, 1);
    VMC(3); BAR();

    // ---- 8 K-steps (BK=64); phase t reads buf t%3, stages t+2 -> (t+2)%3 --
    PH3(0, 2, 2);   // t=0
    PH3(1, 0, 3);   // t=1
    PH3(2, 1, 4);   // t=2
    PH3(0, 2, 5);   // t=3
    PH3(1, 0, 6);   // t=4
    PH3(2, 1, 7);   // t=5
    LDA(0); LDB(0); MM16(); VMC(0); BAR();   // t=6 (drain tile7)
    LDA(1); LDB(1); MM16();                  // t=7

    // ---- epilogue ----
    const int n_base = m0 + wr * 64;
    const int c_base = c0 + wc * 64;
    const int chunk  = ct * 4 + wc;

    float sbv[4];
    #pragma unroll
    for (int ni = 0; ni < 4; ++ni) sbv[ni] = sb[c_base + ni * 16 + lo];

    // v16[r], r = mi*4+j  <->  row n = n_base + (r>>2)*16 + g*4 + (r&3)
    float v16[16];
    #pragma unroll
    for (int mi = 0; mi < 4; ++mi) {
        float4 sa4 = *(const float4*)(sa + n_base + mi * 16 + g * 4);
        const float* sap = (const float*)&sa4;
        #pragma unroll
        for (int j = 0; j < 4; ++j) {
            const float stf = (AMSM_SCALE * L2E) * sap[j];
            float s = 0.f;
            #pragma unroll
            for (int ni = 0; ni < 4; ++ni)
                s += __builtin_amdgcn_exp2f(
                        fmaf((float)acc[mi][ni][j], stf * sbv[ni], BEXP));
            v16[mi * 4 + j] = s;
        }
    }

    // value-halving butterfly over the 16 lo-lanes: lane lo ends with row lo
    const int b0 = lo & 1, b1 = (lo >> 1) & 1, b2 = (lo >> 2) & 1, b3 = (lo >> 3) & 1;
    float v8[8];
    #pragma unroll
    for (int k = 0; k < 8; ++k) {
        float keep = b0 ? v16[2*k+1] : v16[2*k];
        float send = b0 ? v16[2*k]   : v16[2*k+1];
        v8[k] = keep + __shfl_xor(send, 1, 64);
    }
    float v4[4];
    #pragma unroll
    for (int k = 0; k < 4; ++k) {
        float keep = b1 ? v8[2*k+1] : v8[2*k];
        float send = b1 ? v8[2*k]   : v8[2*k+1];
        v4[k] = keep + __shfl_xor(send, 2, 64);
    }
    float v2[2];
    #pragma unroll
    for (int k = 0; k < 2; ++k) {
        float keep = b2 ? v4[2*k+1] : v4[2*k];
        float send = b2 ? v4[2*k]   : v4[2*k+1];
        v2[k] = keep + __shfl_xor(send, 4, 64);
    }
    {
        float keep = b3 ? v2[1] : v2[0];
        float send = b3 ? v2[0] : v2[1];
        float vt = keep + __shfl_xor(send, 8, 64);
        const int n_out = n_base + (lo >> 2) * 16 + g * 4 + (lo & 3);
        psum[(size_t)n_out * CHUNKS + chunk] = vt;
    }
#undef LDA
#undef LDB
#undef MM16
#undef PH3
}

// ---------------- kernel 4: per-row combine + margin fix-up ----------------
__global__ __launch_bounds__(256) void row_reduce(
    const float* __restrict__ psum, const float* __restrict__ tgt,
    float* __restrict__ row_loss, int CHUNKS)
{
    const int n = blockIdx.x;
    const int tid = threadIdx.x;
    __shared__ float sm[256];

    float s = 0.f;
    for (int j = tid; j < CHUNKS; j += 256) s += psum[(size_t)n * CHUNKS + j];
    sm[tid] = s; __syncthreads();
    for (int st = 128; st > 0; st >>= 1) {
        if (tid < st) sm[tid] += sm[tid + st];
        __syncthreads();
    }
    if (tid == 0) {
        const float tl = tgt[n];                       // margined target logit
        // raw sum includes pad cols (96*exp(-30)) and the UNMARGINED target
        // term exp(tl+10.5-30); swap in the margined term exp(tl-30).
        float S = sm[0] - PADC - expf(tl - (AMSM_SCALE - AMSM_SCALE*AMSM_MARGIN))
                + expf(tl - AMSM_SCALE);
        row_loss[n] = (logf(S) + AMSM_SCALE) - tl;
    }
}

// ---------------- kernel 5: mean over rows -> scalar ----------------
__global__ __launch_bounds__(256) void final_reduce(
    const float* __restrict__ row_loss, float* __restrict__ out, int N)
{
    const int tid = threadIdx.x;
    __shared__ float sm[256];
    float s = 0.f;
    for (int i = tid; i < N; i += 256) s += row_loss[i];
    sm[tid] = s; __syncthreads();
    for (int st = 128; st > 0; st >>= 1) {
        if (tid < st) sm[tid] += sm[tid + st];
        __syncthreads();
    }
    if (tid == 0) out[0] = sm[0] / (float)N;
}

// ---------------- launch ----------------
extern "C" void kernel_launch(void* const* d_in, const int* in_sizes, int n_in,
                              void* d_out, int out_size, void* d_ws, size_t ws_size,
                              hipStream_t stream) {
    const float* x  = (const float*)d_in[0];
    const float* W  = (const float*)d_in[1];
    const int*   lb = (const int*)d_in[2];
    float* out = (float*)d_out;

    constexpr int N  = 2048, D = 512, C = 100000;
    constexpr int C_PAD  = CTILES * 256;     // 100096
    constexpr int CHUNKS = CTILES * 4;       // 1564 (one per 64-col wave stripe)

    char* ws = (char*)d_ws;
    auto alloc = [&](size_t bytes) {
        char* p = ws; ws += (bytes + 255) & ~(size_t)255; return p;
    };
    signed char* Wq  = (signed char*)alloc((size_t)C_PAD * D);          // 51.2 MB
    signed char* xqv = (signed char*)alloc((size_t)N * D);              // 1 MB
    float*  sw   = (float*)alloc((size_t)C_PAD * sizeof(float));        // 400 KB
    float*  sx   = (float*)alloc((size_t)N * sizeof(float));
    float*  psum = (float*)alloc((size_t)N * CHUNKS * sizeof(float));   // 12.8 MB
    float*  tgtv = (float*)alloc((size_t)N * sizeof(float));
    float*  rl   = (float*)alloc((size_t)N * sizeof(float));

    rownorm_i8<<<N / 4, 256, 0, stream>>>(x, xqv, sx, N, N);
    rownorm_i8<<<C_PAD / 4, 256, 0, stream>>>(W, Wq, sw, C, C_PAD);
    target_logit<<<N / 4, 256, 0, stream>>>(xqv, Wq, sx, sw, lb, tgtv, N);

    amsm_gemm<<<16 * CTILES, 512, 0, stream>>>(xqv, Wq, sx, sw, psum, CHUNKS);

    row_reduce<<<N, 256, 0, stream>>>(psum, tgtv, rl, CHUNKS);
    final_reduce<<<1, 256, 0, stream>>>(rl, out, N);
}